// Round 1
// baseline (105.970 us; speedup 1.0000x reference)
//
#include <hip/hip_runtime.h>
#include <math.h>

#define BB 4
#define NN 4096
#define MM 512
#define PTS 32                 // points per block
#define CHUNKS 8               // m-chunks per point
#define MCHUNK (MM / CHUNKS)   // 64 triangles per chunk
#define TPB (PTS * CHUNKS)     // 256 threads

__device__ __forceinline__ float safediv(float x, float y) {
    // matches reference _safe_div: x / where(|y|<1e-12, 1.0, y)
    float yy = (fabsf(y) < 1e-12f) ? 1.0f : y;
    return x / yy;  // HIP default: correctly-rounded fp32 divide
}

__device__ __forceinline__ float clip01(float x) {
    return fminf(fmaxf(x, 0.0f), 1.0f);
}

__global__ __launch_bounds__(TPB) void tridist_kernel(
    const float* __restrict__ xyz1, const float* __restrict__ tri1,
    const float* __restrict__ tri2, const float* __restrict__ tri3,
    float* __restrict__ out)
{
#pragma clang fp contract(off)
    __shared__ float sA[MM * 3];
    __shared__ float sB[MM * 3];
    __shared__ float sC[MM * 3];
    __shared__ float rd[TPB];
    __shared__ int   ri[TPB];
    __shared__ int   rr[TPB];

    const int t  = threadIdx.x;
    const int bpb = NN / PTS;              // blocks per batch = 128
    const int b  = blockIdx.x / bpb;
    const int pb = blockIdx.x % bpb;
    const int pt = t & (PTS - 1);          // point within block tile
    const int ch = t >> 5;                 // m-chunk index [0,8)
    const int point = pb * PTS + pt;

    // Stage this batch's triangles into LDS (coalesced).
    const float* g1 = tri1 + (size_t)b * MM * 3;
    const float* g2 = tri2 + (size_t)b * MM * 3;
    const float* g3 = tri3 + (size_t)b * MM * 3;
    for (int i = t; i < MM * 3; i += TPB) {
        sA[i] = g1[i];
        sB[i] = g2[i];
        sC[i] = g3[i];
    }
    __syncthreads();

    const int gidx = b * NN + point;
    const float px = xyz1[gidx * 3 + 0];
    const float py = xyz1[gidx * 3 + 1];
    const float pz = xyz1[gidx * 3 + 2];

    float bestd = INFINITY;
    int bestj = 0, bestr = 6;

    for (int i = 0; i < MCHUNK; ++i) {
        const int j = ch * MCHUNK + i;
        const float ax = sA[j*3+0], ay = sA[j*3+1], az = sA[j*3+2];
        const float bx = sB[j*3+0], by = sB[j*3+1], bz = sB[j*3+2];
        const float cx = sC[j*3+0], cy = sC[j*3+1], cz = sC[j*3+2];

        const float abx = bx-ax, aby = by-ay, abz = bz-az;
        const float acx = cx-ax, acy = cy-ay, acz = cz-az;
        const float cbx = cx-bx, cby = cy-by, cbz = cz-bz;
        const float apx = px-ax, apy = py-ay, apz = pz-az;
        const float bpx = px-bx, bpy = py-by, bpz = pz-bz;
        const float cpx = px-cx, cpy = py-cy, cpz = pz-cz;

        const float d1 = abx*apx + aby*apy + abz*apz;
        const float d2 = acx*apx + acy*apy + acz*apz;
        const float d3 = abx*bpx + aby*bpy + abz*bpz;
        const float d4 = acx*bpx + acy*bpy + acz*bpz;
        const float d5 = abx*cpx + aby*cpy + abz*cpz;
        const float d6 = acx*cpx + acy*cpy + acz*cpz;

        const float vc = d1*d4 - d3*d2;
        const float vb = d5*d2 - d1*d6;
        const float va = d3*d6 - d5*d4;

        const float v_ab = clip01(safediv(d1, d1 - d3));
        const float v_ac = clip01(safediv(d2, d2 - d6));
        const float t43 = d4 - d3;
        const float t56 = d5 - d6;
        const float v_bc = clip01(safediv(t43, t43 + t56));
        const float denom = va + vb + vc;
        const float v_f = safediv(vb, denom);
        const float w_f = safediv(vc, denom);

        // Start from face, override in reference's sel order:
        // bc(5), ac(4), c(2), ab(3), b(1), a(0) — later wins.
        float qx = ax + v_f*abx + w_f*acx;
        float qy = ay + v_f*aby + w_f*acy;
        float qz = az + v_f*abz + w_f*acz;
        int reg = 6;

        const bool c_bc = (va <= 0.0f) && (t43 >= 0.0f) && (t56 >= 0.0f);
        if (c_bc) { qx = bx + v_bc*cbx; qy = by + v_bc*cby; qz = bz + v_bc*cbz; reg = 5; }
        const bool c_ac = (vb <= 0.0f) && (d2 >= 0.0f) && (d6 <= 0.0f);
        if (c_ac) { qx = ax + v_ac*acx; qy = ay + v_ac*acy; qz = az + v_ac*acz; reg = 4; }
        const bool c_c = (d6 >= 0.0f) && (d5 <= d6);
        if (c_c) { qx = cx; qy = cy; qz = cz; reg = 2; }
        const bool c_ab = (vc <= 0.0f) && (d1 >= 0.0f) && (d3 <= 0.0f);
        if (c_ab) { qx = ax + v_ab*abx; qy = ay + v_ab*aby; qz = az + v_ab*abz; reg = 3; }
        const bool c_b = (d3 >= 0.0f) && (d4 <= d3);
        if (c_b) { qx = bx; qy = by; qz = bz; reg = 1; }
        const bool c_a = (d1 <= 0.0f) && (d2 <= 0.0f);
        if (c_a) { qx = ax; qy = ay; qz = az; reg = 0; }

        const float dx = px - qx;
        const float dy = py - qy;
        const float dz = pz - qz;
        const float dist2 = dx*dx + dy*dy + dz*dz;

        // strict < with ascending j: first-occurrence tie-break like np.argmin
        if (dist2 < bestd) { bestd = dist2; bestj = j; bestr = reg; }
    }

    rd[t] = bestd; ri[t] = bestj; rr[t] = bestr;
    __syncthreads();

    if (ch == 0) {
        float bd = rd[pt];
        int bi = ri[pt], br = rr[pt];
        for (int k = 1; k < CHUNKS; ++k) {
            const float d = rd[k * PTS + pt];
            if (d < bd) { bd = d; bi = ri[k * PTS + pt]; br = rr[k * PTS + pt]; }
        }
        // outputs concatenated: dist (f32), region, index — all stored as f32 values
        out[gidx]             = bd;
        out[BB*NN + gidx]     = (float)br;
        out[2*BB*NN + gidx]   = (float)bi;
    }
}

extern "C" void kernel_launch(void* const* d_in, const int* in_sizes, int n_in,
                              void* d_out, int out_size, void* d_ws, size_t ws_size,
                              hipStream_t stream) {
    const float* xyz1 = (const float*)d_in[0];
    const float* tri1 = (const float*)d_in[1];
    const float* tri2 = (const float*)d_in[2];
    const float* tri3 = (const float*)d_in[3];
    float* out = (float*)d_out;

    dim3 grid(BB * (NN / PTS));   // 512 blocks
    dim3 block(TPB);              // 256 threads
    tridist_kernel<<<grid, block, 0, stream>>>(xyz1, tri1, tri2, tri3, out);
}

// Round 3
// 101.160 us; speedup vs baseline: 1.0475x; 1.0475x over previous
//
#include <hip/hip_runtime.h>
#include <math.h>

#define BB 4
#define NN 4096
#define MM 512
#define PTS 32                 // points per block
#define CHUNKS 16              // m-chunks per point
#define MCHUNK (MM / CHUNKS)   // 32 triangles per chunk
#define TPB (PTS * CHUNKS)     // 512 threads

__device__ __forceinline__ float safediv(float x, float y) {
    // matches reference _safe_div: x / where(|y|<1e-12, 1.0, y)
    float yy = (fabsf(y) < 1e-12f) ? 1.0f : y;
    return x / yy;  // HIP default: correctly-rounded fp32 divide
}

__device__ __forceinline__ float clip01(float x) {
    return fminf(fmaxf(x, 0.0f), 1.0f);
}

__global__ __launch_bounds__(TPB) void tridist_kernel(
    const float* __restrict__ xyz1, const float* __restrict__ tri1,
    const float* __restrict__ tri2, const float* __restrict__ tri3,
    float* __restrict__ out)
{
#pragma clang fp contract(off)
    // 3 float4 per triangle: [ax ay az bx | by bz cx cy | cz - - -]
    __shared__ float4 sT[MM * 3];        // 24576 B
    __shared__ float rd[TPB];
    __shared__ int   ri[TPB];
    __shared__ int   rr[TPB];

    const int t   = threadIdx.x;
    const int bpb = NN / PTS;            // 128 blocks per batch
    const int b   = blockIdx.x / bpb;
    const int pb  = blockIdx.x % bpb;
    const int pt  = t & (PTS - 1);
    const int ch  = t >> 5;              // chunk [0,16)
    const int point = pb * PTS + pt;

    // ---- stage: one thread per triangle (TPB == MM), raw coords only ----
    {
        const int jj = t;
        const float* g1 = tri1 + ((size_t)b * MM + jj) * 3;
        const float* g2 = tri2 + ((size_t)b * MM + jj) * 3;
        const float* g3 = tri3 + ((size_t)b * MM + jj) * 3;
        const float ax = g1[0], ay = g1[1], az = g1[2];
        const float bx = g2[0], by = g2[1], bz = g2[2];
        const float cx = g3[0], cy = g3[1], cz = g3[2];
        sT[jj*3 + 0] = make_float4(ax, ay, az, bx);
        sT[jj*3 + 1] = make_float4(by, bz, cx, cy);
        sT[jj*3 + 2] = make_float4(cz, 0.0f, 0.0f, 0.0f);
    }
    __syncthreads();

    const int gidx = b * NN + point;
    const float px = xyz1[gidx * 3 + 0];
    const float py = xyz1[gidx * 3 + 1];
    const float pz = xyz1[gidx * 3 + 2];

    float bestd = INFINITY;
    int bestj = 0, bestr = 6;

    for (int i = 0; i < MCHUNK; ++i) {
        const int j = ch * MCHUNK + i;
        const float4 r0 = sT[j*3 + 0];
        const float4 r1 = sT[j*3 + 1];
        const float4 r2 = sT[j*3 + 2];
        const float ax = r0.x, ay = r0.y, az = r0.z;
        const float bx = r0.w, by = r1.x, bz = r1.y;
        const float cx = r1.z, cy = r1.w, cz = r2.x;

        // ---- identical expression order to the R1-passing kernel ----
        const float abx = bx-ax, aby = by-ay, abz = bz-az;
        const float acx = cx-ax, acy = cy-ay, acz = cz-az;
        const float cbx = cx-bx, cby = cy-by, cbz = cz-bz;
        const float apx = px-ax, apy = py-ay, apz = pz-az;
        const float bpx = px-bx, bpy = py-by, bpz = pz-bz;
        const float cpx = px-cx, cpy = py-cy, cpz = pz-cz;

        const float d1 = abx*apx + aby*apy + abz*apz;
        const float d2 = acx*apx + acy*apy + acz*apz;
        const float d3 = abx*bpx + aby*bpy + abz*bpz;
        const float d4 = acx*bpx + acy*bpy + acz*bpz;
        const float d5 = abx*cpx + aby*cpy + abz*cpz;
        const float d6 = acx*cpx + acy*cpy + acz*cpz;

        const float vc = d1*d4 - d3*d2;
        const float vb = d5*d2 - d1*d6;
        const float va = d3*d6 - d5*d4;

        const float v_ab = clip01(safediv(d1, d1 - d3));
        const float v_ac = clip01(safediv(d2, d2 - d6));
        const float t43 = d4 - d3;
        const float t56 = d5 - d6;
        const float v_bc = clip01(safediv(t43, t43 + t56));
        const float denom = va + vb + vc;
        const float v_f = safediv(vb, denom);
        const float w_f = safediv(vc, denom);

        // Start from face, override in reference's sel order:
        // bc(5), ac(4), c(2), ab(3), b(1), a(0) — later wins.
        float qx = ax + v_f*abx + w_f*acx;
        float qy = ay + v_f*aby + w_f*acy;
        float qz = az + v_f*abz + w_f*acz;
        int reg = 6;

        const bool c_bc = (va <= 0.0f) && (t43 >= 0.0f) && (t56 >= 0.0f);
        if (c_bc) { qx = bx + v_bc*cbx; qy = by + v_bc*cby; qz = bz + v_bc*cbz; reg = 5; }
        const bool c_ac = (vb <= 0.0f) && (d2 >= 0.0f) && (d6 <= 0.0f);
        if (c_ac) { qx = ax + v_ac*acx; qy = ay + v_ac*acy; qz = az + v_ac*acz; reg = 4; }
        const bool c_c = (d6 >= 0.0f) && (d5 <= d6);
        if (c_c) { qx = cx; qy = cy; qz = cz; reg = 2; }
        const bool c_ab = (vc <= 0.0f) && (d1 >= 0.0f) && (d3 <= 0.0f);
        if (c_ab) { qx = ax + v_ab*abx; qy = ay + v_ab*aby; qz = az + v_ab*abz; reg = 3; }
        const bool c_b = (d3 >= 0.0f) && (d4 <= d3);
        if (c_b) { qx = bx; qy = by; qz = bz; reg = 1; }
        const bool c_a = (d1 <= 0.0f) && (d2 <= 0.0f);
        if (c_a) { qx = ax; qy = ay; qz = az; reg = 0; }

        const float dx = px - qx;
        const float dy = py - qy;
        const float dz = pz - qz;
        const float dist2 = dx*dx + dy*dy + dz*dz;

        // strict < with ascending j: first-occurrence tie-break like np.argmin
        if (dist2 < bestd) { bestd = dist2; bestj = j; bestr = reg; }
    }

    rd[t] = bestd; ri[t] = bestj; rr[t] = bestr;
    __syncthreads();

    if (ch == 0) {
        float bd = rd[pt];
        int bi = ri[pt], br = rr[pt];
        for (int k = 1; k < CHUNKS; ++k) {
            const float dk = rd[k * PTS + pt];
            if (dk < bd) { bd = dk; bi = ri[k * PTS + pt]; br = rr[k * PTS + pt]; }
        }
        out[gidx]           = bd;
        out[BB*NN + gidx]   = (float)br;
        out[2*BB*NN + gidx] = (float)bi;
    }
}

extern "C" void kernel_launch(void* const* d_in, const int* in_sizes, int n_in,
                              void* d_out, int out_size, void* d_ws, size_t ws_size,
                              hipStream_t stream) {
    const float* xyz1 = (const float*)d_in[0];
    const float* tri1 = (const float*)d_in[1];
    const float* tri2 = (const float*)d_in[2];
    const float* tri3 = (const float*)d_in[3];
    float* out = (float*)d_out;

    dim3 grid(BB * (NN / PTS));   // 512 blocks
    dim3 block(TPB);              // 512 threads
    tridist_kernel<<<grid, block, 0, stream>>>(xyz1, tri1, tri2, tri3, out);
}

// Round 4
// 86.400 us; speedup vs baseline: 1.2265x; 1.1708x over previous
//
#include <hip/hip_runtime.h>
#include <math.h>

#define BB 4
#define NN 4096
#define MM 512
#define PTS 16                 // points per block
#define CHUNKS 32              // m-chunks per point
#define MCHUNK (MM / CHUNKS)   // 16 triangles per chunk
#define TPB (PTS * CHUNKS)     // 512 threads

// reference _safe_div denominator guard + hw rcp (~1 ulp).
// Error enters q at ~1e-7 absolute -> dist2 error stays relative-class (safe for argmin).
__device__ __forceinline__ float safercp(float y) {
    float yy = (fabsf(y) < 1e-12f) ? 1.0f : y;
    return __builtin_amdgcn_rcpf(yy);
}

__device__ __forceinline__ float clip01(float x) {
    return fminf(fmaxf(x, 0.0f), 1.0f);   // v_med3_f32
}

__global__ __launch_bounds__(TPB) void tridist_kernel(
    const float* __restrict__ xyz1, const float* __restrict__ tri1,
    const float* __restrict__ tri2, const float* __restrict__ tri3,
    float* __restrict__ out)
{
    // 3 float4 per triangle [ax ay az bx | by bz cx cy | cz - - -],
    // padded +1 float4 per 16 triangles so the 4 records a wave touches
    // start on banks {0,4,8,12} (784 B group stride) -> conflict-free.
    __shared__ float4 sT[MM * 3 + MM / 16];   // 25088 B
    __shared__ float rd[TPB];
    __shared__ int   ri[TPB];
    __shared__ int   rr[TPB];

    const int t   = threadIdx.x;
    const int bpb = NN / PTS;            // 256 blocks per batch
    const int b   = blockIdx.x / bpb;
    const int pb  = blockIdx.x % bpb;
    const int pt  = t & (PTS - 1);
    const int ch  = t >> 4;              // chunk [0,32)
    const int point = pb * PTS + pt;

    // ---- stage: one thread per triangle (TPB == MM) ----
    {
        const int jj = t;
        const int base = jj * 3 + (jj >> 4);
        const float* g1 = tri1 + ((size_t)b * MM + jj) * 3;
        const float* g2 = tri2 + ((size_t)b * MM + jj) * 3;
        const float* g3 = tri3 + ((size_t)b * MM + jj) * 3;
        sT[base + 0] = make_float4(g1[0], g1[1], g1[2], g2[0]);
        sT[base + 1] = make_float4(g2[1], g2[2], g3[0], g3[1]);
        sT[base + 2] = make_float4(g3[2], 0.0f, 0.0f, 0.0f);
    }
    __syncthreads();

    const int gidx = b * NN + point;
    const float px = xyz1[gidx * 3 + 0];
    const float py = xyz1[gidx * 3 + 1];
    const float pz = xyz1[gidx * 3 + 2];

    float bestd = INFINITY;
    int bestj = 0, bestr = 6;

    for (int i = 0; i < MCHUNK; ++i) {
        const int j = ch * MCHUNK + i;
        const int base = j * 3 + ch;     // (j>>4)==ch inside this chunk
        const float4 r0 = sT[base + 0];
        const float4 r1 = sT[base + 1];
        const float cz  = sT[base + 2].x;
        const float ax = r0.x, ay = r0.y, az = r0.z;
        const float bx = r0.w, by = r1.x, bz = r1.y;
        const float cx = r1.z, cy = r1.w;

        const float abx = bx-ax, aby = by-ay, abz = bz-az;
        const float acx = cx-ax, acy = cy-ay, acz = cz-az;
        const float cbx = cx-bx, cby = cy-by, cbz = cz-bz;
        const float apx = px-ax, apy = py-ay, apz = pz-az;
        const float bpx = px-bx, bpy = py-by, bpz = pz-bz;
        const float cpx = px-cx, cpy = py-cy, cpz = pz-cz;

        const float d1 = fmaf(abz, apz, fmaf(aby, apy, abx*apx));
        const float d2 = fmaf(acz, apz, fmaf(acy, apy, acx*apx));
        const float d3 = fmaf(abz, bpz, fmaf(aby, bpy, abx*bpx));
        const float d4 = fmaf(acz, bpz, fmaf(acy, bpy, acx*bpx));
        const float d5 = fmaf(abz, cpz, fmaf(aby, cpy, abx*cpx));
        const float d6 = fmaf(acz, cpz, fmaf(acy, cpy, acx*cpx));

        const float vc = fmaf(d1, d4, -(d3*d2));
        const float vb = fmaf(d5, d2, -(d1*d6));
        const float va = fmaf(d3, d6, -(d5*d4));

        const float t43 = d4 - d3;
        const float t56 = d5 - d6;
        const float denom = va + vb + vc;

        const float v_ab = clip01(d1 * safercp(d1 - d3));
        const float v_ac = clip01(d2 * safercp(d2 - d6));
        const float v_bc = clip01(t43 * safercp(t43 + t56));
        const float rden = safercp(denom);
        const float v_f = vb * rden;
        const float w_f = vc * rden;

        // q candidates (|p-q|^2 form keeps dist2 error relative -> argmin-safe)
        float qx = fmaf(w_f, acx, fmaf(v_f, abx, ax));
        float qy = fmaf(w_f, acy, fmaf(v_f, aby, ay));
        float qz = fmaf(w_f, acz, fmaf(v_f, abz, az));
        int reg = 6;

        // reference sel order: bc(5), ac(4), c(2), ab(3), b(1), a(0) - later wins
        const bool c_bc = (va <= 0.0f) && (t43 >= 0.0f) && (t56 >= 0.0f);
        if (c_bc) { qx = fmaf(v_bc, cbx, bx); qy = fmaf(v_bc, cby, by); qz = fmaf(v_bc, cbz, bz); reg = 5; }
        const bool c_ac = (vb <= 0.0f) && (d2 >= 0.0f) && (d6 <= 0.0f);
        if (c_ac) { qx = fmaf(v_ac, acx, ax); qy = fmaf(v_ac, acy, ay); qz = fmaf(v_ac, acz, az); reg = 4; }
        const bool c_c = (d6 >= 0.0f) && (d5 <= d6);
        if (c_c) { qx = cx; qy = cy; qz = cz; reg = 2; }
        const bool c_ab = (vc <= 0.0f) && (d1 >= 0.0f) && (d3 <= 0.0f);
        if (c_ab) { qx = fmaf(v_ab, abx, ax); qy = fmaf(v_ab, aby, ay); qz = fmaf(v_ab, abz, az); reg = 3; }
        const bool c_b = (d3 >= 0.0f) && (d4 <= d3);
        if (c_b) { qx = bx; qy = by; qz = bz; reg = 1; }
        const bool c_a = (d1 <= 0.0f) && (d2 <= 0.0f);
        if (c_a) { qx = ax; qy = ay; qz = az; reg = 0; }

        const float dx = px - qx;
        const float dy = py - qy;
        const float dz = pz - qz;
        const float dist2 = fmaf(dz, dz, fmaf(dy, dy, dx*dx));

        // strict < with ascending j: first-occurrence tie-break like np.argmin
        if (dist2 < bestd) { bestd = dist2; bestj = j; bestr = reg; }
    }

    rd[t] = bestd; ri[t] = bestj; rr[t] = bestr;
    __syncthreads();

    if (ch == 0) {
        float bd = rd[pt];
        int bi = ri[pt], br = rr[pt];
        for (int k = 1; k < CHUNKS; ++k) {
            const float dk = rd[k * PTS + pt];
            if (dk < bd) { bd = dk; bi = ri[k * PTS + pt]; br = rr[k * PTS + pt]; }
        }
        out[gidx]           = bd;
        out[BB*NN + gidx]   = (float)br;
        out[2*BB*NN + gidx] = (float)bi;
    }
}

extern "C" void kernel_launch(void* const* d_in, const int* in_sizes, int n_in,
                              void* d_out, int out_size, void* d_ws, size_t ws_size,
                              hipStream_t stream) {
    const float* xyz1 = (const float*)d_in[0];
    const float* tri1 = (const float*)d_in[1];
    const float* tri2 = (const float*)d_in[2];
    const float* tri3 = (const float*)d_in[3];
    float* out = (float*)d_out;

    dim3 grid(BB * (NN / PTS));   // 1024 blocks -> 4 blocks/CU, 32 waves/CU
    dim3 block(TPB);              // 512 threads
    tridist_kernel<<<grid, block, 0, stream>>>(xyz1, tri1, tri2, tri3, out);
}

// Round 5
// 79.686 us; speedup vs baseline: 1.3298x; 1.0843x over previous
//
#include <hip/hip_runtime.h>
#include <math.h>

#define BB 4
#define NN 4096
#define MM 512
#define PTS 16                 // point-slots per block (x2 points per thread)
#define NPT 2                  // points per thread
#define CHUNKS 32              // m-chunks
#define MCHUNK (MM / CHUNKS)   // 16 triangles per chunk
#define TPB 512

// reference _safe_div guard + hw rcp (~1 ulp) -- relative-class error, argmin-safe (validated R4)
__device__ __forceinline__ float safercp(float y) {
    float yy = (fabsf(y) < 1e-12f) ? 1.0f : y;
    return __builtin_amdgcn_rcpf(yy);
}

__device__ __forceinline__ float clip01(float x) {
    return fminf(fmaxf(x, 0.0f), 1.0f);   // v_med3_f32
}

__global__ __launch_bounds__(TPB) void tridist_kernel(
    const float* __restrict__ xyz1, const float* __restrict__ tri1,
    const float* __restrict__ tri2, const float* __restrict__ tri3,
    float* __restrict__ out)
{
    // 7 float4 per triangle record:
    // r0[ax ay az bx] r1[by bz cx cy] r2[cz abx aby abz] r3[acx acy acz cbx]
    // r4[cby cbz ab.a ab.b] r5[ab.c ac.a ac.b ac.c] r6[rab2 rac2 rcb2 rden]
    // +1 float4 pad per 16 records: the 4 records a wave touches (j stride 16)
    // start on banks {0,4,8,12} -> conflict-free broadcast reads.
    __shared__ float4 sT[MM * 7 + MM / 16];   // 57856 B; aliased for reduction after loop

    const int t  = threadIdx.x;
    const int b  = blockIdx.x >> 7;          // 128 blocks per batch
    const int pb = blockIdx.x & 127;
    const int pt = t & (PTS - 1);
    const int ch = t >> 4;                   // chunk [0,32)

    // ---- stage + per-triangle precompute: one thread per triangle (TPB == MM) ----
    {
        const int jj = t;
        const float* g1 = tri1 + ((size_t)b * MM + jj) * 3;
        const float* g2 = tri2 + ((size_t)b * MM + jj) * 3;
        const float* g3 = tri3 + ((size_t)b * MM + jj) * 3;
        const float ax = g1[0], ay = g1[1], az = g1[2];
        const float bx = g2[0], by = g2[1], bz = g2[2];
        const float cx = g3[0], cy = g3[1], cz = g3[2];
        const float abx = bx-ax, aby = by-ay, abz = bz-az;
        const float acx = cx-ax, acy = cy-ay, acz = cz-az;
        const float cbx = cx-bx, cby = cy-by, cbz = cz-bz;
        const float aba  = fmaf(abz, az, fmaf(aby, ay, abx*ax));
        const float abb  = fmaf(abz, bz, fmaf(aby, by, abx*bx));
        const float abc_ = fmaf(abz, cz, fmaf(aby, cy, abx*cx));
        const float aca  = fmaf(acz, az, fmaf(acy, ay, acx*ax));
        const float acb_ = fmaf(acz, bz, fmaf(acy, by, acx*bx));
        const float acc_ = fmaf(acz, cz, fmaf(acy, cy, acx*cx));
        const float ab2  = fmaf(abz, abz, fmaf(aby, aby, abx*abx));   // == d1-d3
        const float ac2  = fmaf(acz, acz, fmaf(acy, acy, acx*acx));   // == d2-d6
        const float cb2  = fmaf(cbz, cbz, fmaf(cby, cby, cbx*cbx));   // == t43+t56
        const float abac = fmaf(abz, acz, fmaf(aby, acy, abx*acx));
        const float gdet = fmaf(ab2, ac2, -(abac*abac));              // == va+vb+vc (Gram)
        const int base = jj * 7 + (jj >> 4);
        sT[base + 0] = make_float4(ax, ay, az, bx);
        sT[base + 1] = make_float4(by, bz, cx, cy);
        sT[base + 2] = make_float4(cz, abx, aby, abz);
        sT[base + 3] = make_float4(acx, acy, acz, cbx);
        sT[base + 4] = make_float4(cby, cbz, aba, abb);
        sT[base + 5] = make_float4(abc_, aca, acb_, acc_);
        sT[base + 6] = make_float4(safercp(ab2), safercp(ac2), safercp(cb2), safercp(gdet));
    }
    __syncthreads();

    // ---- 2 points per thread ----
    float px[NPT], py[NPT], pz[NPT];
#pragma unroll
    for (int np = 0; np < NPT; ++np) {
        const int gi = b * NN + pb * 32 + np * PTS + pt;
        px[np] = xyz1[gi*3 + 0];
        py[np] = xyz1[gi*3 + 1];
        pz[np] = xyz1[gi*3 + 2];
    }

    float bestd[NPT] = {INFINITY, INFINITY};
    int   bestc[NPT] = {0, 0};           // (j<<3)|reg

    for (int i = 0; i < MCHUNK; ++i) {
        const int j = ch * MCHUNK + i;
        const int base = j * 7 + ch;     // (j>>4)==ch within this chunk
        const float4 r0 = sT[base + 0];
        const float4 r1 = sT[base + 1];
        const float4 r2 = sT[base + 2];
        const float4 r3 = sT[base + 3];
        const float4 r4 = sT[base + 4];
        const float4 r5 = sT[base + 5];
        const float4 r6 = sT[base + 6];
        const float ax = r0.x, ay = r0.y, az = r0.z;
        const float bx = r0.w, by = r1.x, bz = r1.y;
        const float cx = r1.z, cy = r1.w, cz = r2.x;
        const float abx = r2.y, aby = r2.z, abz = r2.w;
        const float acx = r3.x, acy = r3.y, acz = r3.z;
        const float cbx = r3.w, cby = r4.x, cbz = r4.y;
        const float aba = r4.z, abb = r4.w;
        const float abc_ = r5.x, aca = r5.y, acb_ = r5.z, acc_ = r5.w;
        const float rab2 = r6.x, rac2 = r6.y, rcb2 = r6.z, rden = r6.w;

#pragma unroll
        for (int np = 0; np < NPT; ++np) {
            const float s1 = fmaf(abz, pz[np], fmaf(aby, py[np], abx*px[np]));
            const float s2 = fmaf(acz, pz[np], fmaf(acy, py[np], acx*px[np]));
            const float d1 = s1 - aba, d3 = s1 - abb, d5 = s1 - abc_;
            const float d2 = s2 - aca, d4 = s2 - acb_, d6 = s2 - acc_;

            const float vc = fmaf(d1, d4, -(d3*d2));
            const float vb = fmaf(d5, d2, -(d1*d6));
            const float va = fmaf(d3, d6, -(d5*d4));

            const float t43 = d4 - d3;
            const float t56 = d5 - d6;

            const float v_ab = clip01(d1 * rab2);
            const float v_ac = clip01(d2 * rac2);
            const float v_bc = clip01(t43 * rcb2);
            const float v_f = vb * rden;
            const float w_f = vc * rden;

            float qx = fmaf(w_f, acx, fmaf(v_f, abx, ax));
            float qy = fmaf(w_f, acy, fmaf(v_f, aby, ay));
            float qz = fmaf(w_f, acz, fmaf(v_f, abz, az));
            int reg = 6;

            // reference sel order: bc(5), ac(4), c(2), ab(3), b(1), a(0) - later wins
            const bool c_bc = (va <= 0.0f) && (t43 >= 0.0f) && (t56 >= 0.0f);
            if (c_bc) { qx = fmaf(v_bc, cbx, bx); qy = fmaf(v_bc, cby, by); qz = fmaf(v_bc, cbz, bz); reg = 5; }
            const bool c_ac = (vb <= 0.0f) && (d2 >= 0.0f) && (d6 <= 0.0f);
            if (c_ac) { qx = fmaf(v_ac, acx, ax); qy = fmaf(v_ac, acy, ay); qz = fmaf(v_ac, acz, az); reg = 4; }
            const bool c_c = (d6 >= 0.0f) && (d5 <= d6);
            if (c_c) { qx = cx; qy = cy; qz = cz; reg = 2; }
            const bool c_ab = (vc <= 0.0f) && (d1 >= 0.0f) && (d3 <= 0.0f);
            if (c_ab) { qx = fmaf(v_ab, abx, ax); qy = fmaf(v_ab, aby, ay); qz = fmaf(v_ab, abz, az); reg = 3; }
            const bool c_b = (d3 >= 0.0f) && (d4 <= d3);
            if (c_b) { qx = bx; qy = by; qz = bz; reg = 1; }
            const bool c_a = (d1 <= 0.0f) && (d2 <= 0.0f);
            if (c_a) { qx = ax; qy = ay; qz = az; reg = 0; }

            const float dx = px[np] - qx;
            const float dy = py[np] - qy;
            const float dz = pz[np] - qz;
            const float dist2 = fmaf(dz, dz, fmaf(dy, dy, dx*dx));

            // strict < with ascending j: first-occurrence tie-break like np.argmin
            if (dist2 < bestd[np]) { bestd[np] = dist2; bestc[np] = (j << 3) | reg; }
        }
    }

    // ---- reduction over chunks (reuse sT as scratch) ----
    __syncthreads();
    float* rdu = (float*)sT;                 // NPT*TPB floats
    int*   rcu = (int*)(rdu + NPT * TPB);    // NPT*TPB ints (8 KiB total << 57.9 KiB)
#pragma unroll
    for (int np = 0; np < NPT; ++np) {
        rdu[np * TPB + t] = bestd[np];
        rcu[np * TPB + t] = bestc[np];
    }
    __syncthreads();

    if (t < 32) {
        const int np = t >> 4;
        const int p  = t & 15;
        float bd = INFINITY; int bc = 0;
        for (int k = 0; k < CHUNKS; ++k) {
            const float dk = rdu[np * TPB + k * PTS + p];
            const int   ck = rcu[np * TPB + k * PTS + p];
            if (dk < bd) { bd = dk; bc = ck; }   // ascending k == ascending j
        }
        const int gidx = b * NN + pb * 32 + t;   // t = np*16+p
        out[gidx]             = bd;
        out[BB*NN + gidx]     = (float)(bc & 7);
        out[2*BB*NN + gidx]   = (float)(bc >> 3);
    }
}

extern "C" void kernel_launch(void* const* d_in, const int* in_sizes, int n_in,
                              void* d_out, int out_size, void* d_ws, size_t ws_size,
                              hipStream_t stream) {
    const float* xyz1 = (const float*)d_in[0];
    const float* tri1 = (const float*)d_in[1];
    const float* tri2 = (const float*)d_in[2];
    const float* tri3 = (const float*)d_in[3];
    float* out = (float*)d_out;

    dim3 grid(BB * (NN / 32));    // 512 blocks -> 2 blocks/CU, 16 waves/CU (ILP-2/thread)
    dim3 block(TPB);              // 512 threads
    tridist_kernel<<<grid, block, 0, stream>>>(xyz1, tri1, tri2, tri3, out);
}

// Round 6
// 74.251 us; speedup vs baseline: 1.4272x; 1.0732x over previous
//
#include <hip/hip_runtime.h>
#include <math.h>

#define BB 4
#define NN 4096
#define MM 512
#define PTS 16                 // point-slots per block (x2 points per thread)
#define NPT 2                  // points per thread
#define CHUNKS 32              // m-chunks
#define MCHUNK (MM / CHUNKS)   // 16 triangles per chunk
#define TPB 512

// reference _safe_div guard + hw rcp (~1 ulp) -- relative-class error, argmin-safe (validated R4/R5)
__device__ __forceinline__ float safercp(float y) {
    float yy = (fabsf(y) < 1e-12f) ? 1.0f : y;
    return __builtin_amdgcn_rcpf(yy);
}

// exact IEEE version for phase-2 (matches reference bit-order, validated R1/R3)
__device__ __forceinline__ float safediv(float x, float y) {
    float yy = (fabsf(y) < 1e-12f) ? 1.0f : y;
    return x / yy;
}

__device__ __forceinline__ float clip01(float x) {
    return fminf(fmaxf(x, 0.0f), 1.0f);   // v_med3_f32
}

// Phase 2: exact reference-ordered Ericson for ONE pair (R1-validated numerics).
__device__ void exact_pair(float px, float py, float pz,
                           float ax, float ay, float az,
                           float bx, float by, float bz,
                           float cx, float cy, float cz,
                           float* dist2_out, int* reg_out) {
#pragma clang fp contract(off)
    const float abx = bx-ax, aby = by-ay, abz = bz-az;
    const float acx = cx-ax, acy = cy-ay, acz = cz-az;
    const float cbx = cx-bx, cby = cy-by, cbz = cz-bz;
    const float apx = px-ax, apy = py-ay, apz = pz-az;
    const float bpx = px-bx, bpy = py-by, bpz = pz-bz;
    const float cpx = px-cx, cpy = py-cy, cpz = pz-cz;

    const float d1 = abx*apx + aby*apy + abz*apz;
    const float d2 = acx*apx + acy*apy + acz*apz;
    const float d3 = abx*bpx + aby*bpy + abz*bpz;
    const float d4 = acx*bpx + acy*bpy + acz*bpz;
    const float d5 = abx*cpx + aby*cpy + abz*cpz;
    const float d6 = acx*cpx + acy*cpy + acz*cpz;

    const float vc = d1*d4 - d3*d2;
    const float vb = d5*d2 - d1*d6;
    const float va = d3*d6 - d5*d4;

    const float v_ab = clip01(safediv(d1, d1 - d3));
    const float v_ac = clip01(safediv(d2, d2 - d6));
    const float t43 = d4 - d3;
    const float t56 = d5 - d6;
    const float v_bc = clip01(safediv(t43, t43 + t56));
    const float denom = va + vb + vc;
    const float v_f = safediv(vb, denom);
    const float w_f = safediv(vc, denom);

    float qx = ax + v_f*abx + w_f*acx;
    float qy = ay + v_f*aby + w_f*acy;
    float qz = az + v_f*abz + w_f*acz;
    int reg = 6;
    const bool c_bc = (va <= 0.0f) && (t43 >= 0.0f) && (t56 >= 0.0f);
    if (c_bc) { qx = bx + v_bc*cbx; qy = by + v_bc*cby; qz = bz + v_bc*cbz; reg = 5; }
    const bool c_ac = (vb <= 0.0f) && (d2 >= 0.0f) && (d6 <= 0.0f);
    if (c_ac) { qx = ax + v_ac*acx; qy = ay + v_ac*acy; qz = az + v_ac*acz; reg = 4; }
    const bool c_c = (d6 >= 0.0f) && (d5 <= d6);
    if (c_c) { qx = cx; qy = cy; qz = cz; reg = 2; }
    const bool c_ab = (vc <= 0.0f) && (d1 >= 0.0f) && (d3 <= 0.0f);
    if (c_ab) { qx = ax + v_ab*abx; qy = ay + v_ab*aby; qz = az + v_ab*abz; reg = 3; }
    const bool c_b = (d3 >= 0.0f) && (d4 <= d3);
    if (c_b) { qx = bx; qy = by; qz = bz; reg = 1; }
    const bool c_a = (d1 <= 0.0f) && (d2 <= 0.0f);
    if (c_a) { qx = ax; qy = ay; qz = az; reg = 0; }

    const float dx = px - qx;
    const float dy = py - qy;
    const float dz = pz - qz;
    *dist2_out = dx*dx + dy*dy + dz*dz;
    *reg_out = reg;
}

__global__ __launch_bounds__(TPB) void tridist_kernel(
    const float* __restrict__ xyz1, const float* __restrict__ tri1,
    const float* __restrict__ tri2, const float* __restrict__ tri3,
    float* __restrict__ out)
{
    // 7 float4 per record: r0[a.xyz rden] r1[ab.xyz rab2] r2[ac.xyz rac2]
    // r3[cb.xyz rcb2] r4[ab.a ab.b ab.c cx] r5[ac.a ac.b ac.c cy] r6[b.xyz cz]
    // +1 float4 pad per 16 records -> wave's 4 record groups land on banks
    // {0,4,8,12} -> conflict-free (validated R5: SQ_LDS_BANK_CONFLICT==0).
    __shared__ float4 sT[MM * 7 + MM / 16];   // 57856 B
    __shared__ float  sPd[NPT][128];          // per-(wave,pt) partials
    __shared__ int    sPj[NPT][128];          // 2 KiB total -> 59904 B <= 64 KiB

    const int t  = threadIdx.x;
    const int b  = blockIdx.x >> 7;          // 128 blocks per batch
    const int pb = blockIdx.x & 127;
    const int pt = t & (PTS - 1);
    const int ch = t >> 4;                   // chunk [0,32)

    // ---- stage + per-triangle precompute (one thread per triangle) ----
    {
        const int jj = t;
        const float* g1 = tri1 + ((size_t)b * MM + jj) * 3;
        const float* g2 = tri2 + ((size_t)b * MM + jj) * 3;
        const float* g3 = tri3 + ((size_t)b * MM + jj) * 3;
        const float ax = g1[0], ay = g1[1], az = g1[2];
        const float bx = g2[0], by = g2[1], bz = g2[2];
        const float cx = g3[0], cy = g3[1], cz = g3[2];
        const float abx = bx-ax, aby = by-ay, abz = bz-az;
        const float acx = cx-ax, acy = cy-ay, acz = cz-az;
        const float cbx = cx-bx, cby = cy-by, cbz = cz-bz;
        const float aba  = fmaf(abz, az, fmaf(aby, ay, abx*ax));
        const float abb  = fmaf(abz, bz, fmaf(aby, by, abx*bx));
        const float abc_ = fmaf(abz, cz, fmaf(aby, cy, abx*cx));
        const float aca  = fmaf(acz, az, fmaf(acy, ay, acx*ax));
        const float acb_ = fmaf(acz, bz, fmaf(acy, by, acx*bx));
        const float acc_ = fmaf(acz, cz, fmaf(acy, cy, acx*cx));
        const float ab2  = fmaf(abz, abz, fmaf(aby, aby, abx*abx));   // d1-d3
        const float ac2  = fmaf(acz, acz, fmaf(acy, acy, acx*acx));   // d2-d6
        const float cb2  = fmaf(cbz, cbz, fmaf(cby, cby, cbx*cbx));   // t43+t56
        const float abac = fmaf(abz, acz, fmaf(aby, acy, abx*acx));
        const float gdet = fmaf(ab2, ac2, -(abac*abac));              // va+vb+vc (Gram)
        const int base = jj * 7 + (jj >> 4);
        sT[base + 0] = make_float4(ax, ay, az, safercp(gdet));
        sT[base + 1] = make_float4(abx, aby, abz, safercp(ab2));
        sT[base + 2] = make_float4(acx, acy, acz, safercp(ac2));
        sT[base + 3] = make_float4(cbx, cby, cbz, safercp(cb2));
        sT[base + 4] = make_float4(aba, abb, abc_, cx);
        sT[base + 5] = make_float4(aca, acb_, acc_, cy);
        sT[base + 6] = make_float4(bx, by, bz, cz);
    }
    __syncthreads();

    float px[NPT], py[NPT], pz[NPT];
#pragma unroll
    for (int np = 0; np < NPT; ++np) {
        const int gi = b * NN + pb * 32 + np * PTS + pt;
        px[np] = xyz1[gi*3 + 0];
        py[np] = xyz1[gi*3 + 1];
        pz[np] = xyz1[gi*3 + 2];
    }

    float bestd[NPT] = {INFINITY, INFINITY};
    int   bestj[NPT] = {0, 0};

    // ---- phase 1: min-form distance only (no region, no cascade) ----
    for (int i = 0; i < MCHUNK; ++i) {
        const int j = ch * MCHUNK + i;
        const int base = j * 7 + ch;         // (j>>4)==ch within chunk
        const float4 r0 = sT[base + 0];
        const float4 r1 = sT[base + 1];
        const float4 r2 = sT[base + 2];
        const float4 r3 = sT[base + 3];
        const float4 r4 = sT[base + 4];
        const float4 r5 = sT[base + 5];
        const float ax = r0.x, ay = r0.y, az = r0.z, rden = r0.w;
        const float abx = r1.x, aby = r1.y, abz = r1.z, rab2 = r1.w;
        const float acx = r2.x, acy = r2.y, acz = r2.z, rac2 = r2.w;
        const float cbx = r3.x, cby = r3.y, cbz = r3.z, rcb2 = r3.w;
        const float aba = r4.x, abb = r4.y, abc_ = r4.z;
        const float aca = r5.x, acb_ = r5.y, acc_ = r5.z;

#pragma unroll
        for (int np = 0; np < NPT; ++np) {
            const float s1 = fmaf(abz, pz[np], fmaf(aby, py[np], abx*px[np]));
            const float s2 = fmaf(acz, pz[np], fmaf(acy, py[np], acx*px[np]));
            const float d1 = s1 - aba, d3 = s1 - abb, d5 = s1 - abc_;
            const float d2 = s2 - aca, d4 = s2 - acb_, d6 = s2 - acc_;

            const float vc = fmaf(d1, d4, -(d3*d2));
            const float vb = fmaf(d5, d2, -(d1*d6));
            const float va = fmaf(d3, d6, -(d5*d4));
            const float t43 = d4 - d3;

            const float v_ab = clip01(d1 * rab2);
            const float v_ac = clip01(d2 * rac2);
            const float v_bc = clip01(t43 * rcb2);
            const float v_f = vb * rden;
            const float w_f = vc * rden;

            const float apx = px[np] - ax, apy = py[np] - ay, apz = pz[np] - az;
            const float bpx = apx - abx, bpy = apy - aby, bpz = apz - abz;

            // candidate distances (all relative-class)
            float ex = fmaf(-v_ab, abx, apx), ey = fmaf(-v_ab, aby, apy), ez = fmaf(-v_ab, abz, apz);
            const float dAB = fmaf(ez, ez, fmaf(ey, ey, ex*ex));
            ex = fmaf(-v_ac, acx, apx); ey = fmaf(-v_ac, acy, apy); ez = fmaf(-v_ac, acz, apz);
            const float dAC = fmaf(ez, ez, fmaf(ey, ey, ex*ex));
            ex = fmaf(-v_bc, cbx, bpx); ey = fmaf(-v_bc, cby, bpy); ez = fmaf(-v_bc, cbz, bpz);
            const float dBC = fmaf(ez, ez, fmaf(ey, ey, ex*ex));
            ex = fmaf(-w_f, acx, fmaf(-v_f, abx, apx));
            ey = fmaf(-w_f, acy, fmaf(-v_f, aby, apy));
            ez = fmaf(-w_f, acz, fmaf(-v_f, abz, apz));
            const float dF = fmaf(ez, ez, fmaf(ey, ey, ex*ex));

            const bool inside = (va >= 0.0f) && (vb >= 0.0f) && (vc >= 0.0f);
            const float dseg = fminf(fminf(dAB, dAC), dBC);
            const float dist2 = inside ? dF : dseg;

            // strict < ascending j: first-occurrence tie-break like np.argmin
            if (dist2 < bestd[np]) { bestd[np] = dist2; bestj[np] = j; }
        }
    }

    // ---- in-wave butterfly over the 4 chunks this wave holds ----
#pragma unroll
    for (int np = 0; np < NPT; ++np) {
        for (int off = 16; off <= 32; off <<= 1) {
            const float od = __shfl_xor(bestd[np], off, 64);
            const int   oj = __shfl_xor(bestj[np], off, 64);
            if (od < bestd[np] || (od == bestd[np] && oj < bestj[np])) {
                bestd[np] = od; bestj[np] = oj;
            }
        }
    }
    const int lane = t & 63;
    const int w    = t >> 6;                 // wave [0,8)
    if (lane < PTS) {
#pragma unroll
        for (int np = 0; np < NPT; ++np) {
            sPd[np][w * PTS + lane] = bestd[np];
            sPj[np][w * PTS + lane] = bestj[np];
        }
    }
    __syncthreads();

    // ---- final reduce + phase 2: exact recompute for the winner ----
    if (t < 32) {
        const int np = t >> 4;
        const int p  = t & 15;
        float bd = INFINITY; int bj = 0;
        for (int k = 0; k < 8; ++k) {        // waves ascend -> chunks ascend -> j ascends
            const float dk = sPd[np][k * PTS + p];
            const int   jk = sPj[np][k * PTS + p];
            if (dk < bd || (dk == bd && jk < bj)) { bd = dk; bj = jk; }
        }
        const int base = bj * 7 + (bj >> 4);
        const float4 r0 = sT[base + 0];
        const float4 r4 = sT[base + 4];
        const float4 r5 = sT[base + 5];
        const float4 r6 = sT[base + 6];
        const int gidx = b * NN + pb * 32 + t;   // t == np*16 + p
        float dist2; int reg;
        exact_pair(xyz1[gidx*3+0], xyz1[gidx*3+1], xyz1[gidx*3+2],
                   r0.x, r0.y, r0.z,            // a
                   r6.x, r6.y, r6.z,            // b
                   r4.w, r5.w, r6.w,            // c
                   &dist2, &reg);
        out[gidx]             = dist2;
        out[BB*NN + gidx]     = (float)reg;
        out[2*BB*NN + gidx]   = (float)bj;
    }
}

extern "C" void kernel_launch(void* const* d_in, const int* in_sizes, int n_in,
                              void* d_out, int out_size, void* d_ws, size_t ws_size,
                              hipStream_t stream) {
    const float* xyz1 = (const float*)d_in[0];
    const float* tri1 = (const float*)d_in[1];
    const float* tri2 = (const float*)d_in[2];
    const float* tri3 = (const float*)d_in[3];
    float* out = (float*)d_out;

    dim3 grid(BB * (NN / 32));    // 512 blocks -> 2 blocks/CU, 16 waves/CU
    dim3 block(TPB);              // 512 threads
    tridist_kernel<<<grid, block, 0, stream>>>(xyz1, tri1, tri2, tri3, out);
}

// Round 7
// 73.537 us; speedup vs baseline: 1.4410x; 1.0097x over previous
//
#include <hip/hip_runtime.h>
#include <math.h>

#define BB 4
#define NN 4096
#define MM 512
#define PTS 8                  // point-slots per block
#define NPT 4                  // points per thread (block covers 32 points)
#define CHUNKS 64              // m-chunks
#define MCHUNK (MM / CHUNKS)   // 8 triangles per chunk
#define TPB 512

// reference _safe_div guard + hw rcp (~1 ulp) -- relative-class error, argmin-safe (R4-R6 validated)
__device__ __forceinline__ float safercp(float y) {
    float yy = (fabsf(y) < 1e-12f) ? 1.0f : y;
    return __builtin_amdgcn_rcpf(yy);
}

// exact IEEE version for phase-2 (matches reference bit-order, validated R1/R3/R6)
__device__ __forceinline__ float safediv(float x, float y) {
    float yy = (fabsf(y) < 1e-12f) ? 1.0f : y;
    return x / yy;
}

__device__ __forceinline__ float clip01(float x) {
    return fminf(fmaxf(x, 0.0f), 1.0f);   // v_med3_f32
}

// Phase 2: exact reference-ordered Ericson for ONE pair (R1-validated numerics).
__device__ void exact_pair(float px, float py, float pz,
                           float ax, float ay, float az,
                           float bx, float by, float bz,
                           float cx, float cy, float cz,
                           float* dist2_out, int* reg_out) {
#pragma clang fp contract(off)
    const float abx = bx-ax, aby = by-ay, abz = bz-az;
    const float acx = cx-ax, acy = cy-ay, acz = cz-az;
    const float cbx = cx-bx, cby = cy-by, cbz = cz-bz;
    const float apx = px-ax, apy = py-ay, apz = pz-az;
    const float bpx = px-bx, bpy = py-by, bpz = pz-bz;
    const float cpx = px-cx, cpy = py-cy, cpz = pz-cz;

    const float d1 = abx*apx + aby*apy + abz*apz;
    const float d2 = acx*apx + acy*apy + acz*apz;
    const float d3 = abx*bpx + aby*bpy + abz*bpz;
    const float d4 = acx*bpx + acy*bpy + acz*bpz;
    const float d5 = abx*cpx + aby*cpy + abz*cpz;
    const float d6 = acx*cpx + acy*cpy + acz*cpz;

    const float vc = d1*d4 - d3*d2;
    const float vb = d5*d2 - d1*d6;
    const float va = d3*d6 - d5*d4;

    const float v_ab = clip01(safediv(d1, d1 - d3));
    const float v_ac = clip01(safediv(d2, d2 - d6));
    const float t43 = d4 - d3;
    const float t56 = d5 - d6;
    const float v_bc = clip01(safediv(t43, t43 + t56));
    const float denom = va + vb + vc;
    const float v_f = safediv(vb, denom);
    const float w_f = safediv(vc, denom);

    float qx = ax + v_f*abx + w_f*acx;
    float qy = ay + v_f*aby + w_f*acy;
    float qz = az + v_f*abz + w_f*acz;
    int reg = 6;
    const bool c_bc = (va <= 0.0f) && (t43 >= 0.0f) && (t56 >= 0.0f);
    if (c_bc) { qx = bx + v_bc*cbx; qy = by + v_bc*cby; qz = bz + v_bc*cbz; reg = 5; }
    const bool c_ac = (vb <= 0.0f) && (d2 >= 0.0f) && (d6 <= 0.0f);
    if (c_ac) { qx = ax + v_ac*acx; qy = ay + v_ac*acy; qz = az + v_ac*acz; reg = 4; }
    const bool c_c = (d6 >= 0.0f) && (d5 <= d6);
    if (c_c) { qx = cx; qy = cy; qz = cz; reg = 2; }
    const bool c_ab = (vc <= 0.0f) && (d1 >= 0.0f) && (d3 <= 0.0f);
    if (c_ab) { qx = ax + v_ab*abx; qy = ay + v_ab*aby; qz = az + v_ab*abz; reg = 3; }
    const bool c_b = (d3 >= 0.0f) && (d4 <= d3);
    if (c_b) { qx = bx; qy = by; qz = bz; reg = 1; }
    const bool c_a = (d1 <= 0.0f) && (d2 <= 0.0f);
    if (c_a) { qx = ax; qy = ay; qz = az; reg = 0; }

    const float dx = px - qx;
    const float dy = py - qy;
    const float dz = pz - qz;
    *dist2_out = dx*dx + dy*dy + dz*dz;
    *reg_out = reg;
}

__global__ __launch_bounds__(TPB) void tridist_kernel(
    const float* __restrict__ xyz1, const float* __restrict__ tri1,
    const float* __restrict__ tri2, const float* __restrict__ tri3,
    float* __restrict__ out)
{
    // 6 float4 per record:
    //  r0[a.xyz  nna(-n.a)] r1[ab.xyz rab2] r2[ac.xyz rac2] r3[cb.xyz rcb2]
    //  r4[n.xyz  abac]      r5[naba(-ab.a) naca(-ac.a) ab2 ac2]
    // +1 float4 pad per group of 8 records (49 float4 / group): the 8 records a
    // wave touches start on banks {0,4,...,28} -> all 32 banks, conflict-free.
    __shared__ float4 sT[(MM / 8) * 49];      // 3136 float4 = 50176 B
    __shared__ float  sPd[NPT][64];           // per-(wave,pt) partials
    __shared__ int    sPj[NPT][64];           // total LDS 52224 B -> 2 blocks/CU

    const int t  = threadIdx.x;
    const int b  = blockIdx.x >> 7;          // 128 blocks per batch
    const int pb = blockIdx.x & 127;
    const int pt = t & (PTS - 1);
    const int ch = t >> 3;                   // chunk [0,64)

    // ---- stage + per-triangle precompute (one thread per triangle, TPB==MM) ----
    {
        const int jj = t;
        const float* g1 = tri1 + ((size_t)b * MM + jj) * 3;
        const float* g2 = tri2 + ((size_t)b * MM + jj) * 3;
        const float* g3 = tri3 + ((size_t)b * MM + jj) * 3;
        const float ax = g1[0], ay = g1[1], az = g1[2];
        const float bx = g2[0], by = g2[1], bz = g2[2];
        const float cx = g3[0], cy = g3[1], cz = g3[2];
        const float abx = bx-ax, aby = by-ay, abz = bz-az;
        const float acx = cx-ax, acy = cy-ay, acz = cz-az;
        const float cbx = cx-bx, cby = cy-by, cbz = cz-bz;
        const float aba  = fmaf(abz, az, fmaf(aby, ay, abx*ax));   // ab.a
        const float aca  = fmaf(acz, az, fmaf(acy, ay, acx*ax));   // ac.a
        const float ab2  = fmaf(abz, abz, fmaf(aby, aby, abx*abx));   // == d1-d3
        const float ac2  = fmaf(acz, acz, fmaf(acy, acy, acx*acx));   // == d2-d6
        const float cb2  = fmaf(cbz, cbz, fmaf(cby, cby, cbx*cbx));   // == t43+t56
        const float abac = fmaf(abz, acz, fmaf(aby, acy, abx*acx));   // ab.ac
        // unit normal: n_raw = ab x ac; |n_raw|^2 == gram (Lagrange identity)
        const float nrx = fmaf(aby, acz, -(abz*acy));
        const float nry = fmaf(abz, acx, -(abx*acz));
        const float nrz = fmaf(abx, acy, -(aby*acx));
        const float n2  = fmaf(nrz, nrz, fmaf(nry, nry, nrx*nrx));
        const float rn  = __builtin_amdgcn_rsqf(fmaxf(n2, 1e-30f));
        const float nx = nrx*rn, ny = nry*rn, nz = nrz*rn;
        const float nna = -fmaf(nz, az, fmaf(ny, ay, nx*ax));      // -n.a
        const int base = (jj >> 3) * 49 + (jj & 7) * 6;
        sT[base + 0] = make_float4(ax, ay, az, nna);
        sT[base + 1] = make_float4(abx, aby, abz, safercp(ab2));
        sT[base + 2] = make_float4(acx, acy, acz, safercp(ac2));
        sT[base + 3] = make_float4(cbx, cby, cbz, safercp(cb2));
        sT[base + 4] = make_float4(nx, ny, nz, abac);
        sT[base + 5] = make_float4(-aba, -aca, ab2, ac2);
    }
    __syncthreads();

    float px[NPT], py[NPT], pz[NPT];
#pragma unroll
    for (int np = 0; np < NPT; ++np) {
        const int gi = b * NN + pb * 32 + np * PTS + pt;
        px[np] = xyz1[gi*3 + 0];
        py[np] = xyz1[gi*3 + 1];
        pz[np] = xyz1[gi*3 + 2];
    }

    float bestd[NPT] = {INFINITY, INFINITY, INFINITY, INFINITY};
    int   bestj[NPT] = {0, 0, 0, 0};

    // ---- phase 1: min-form distance (normal-trick face, hoisted d's) ----
    for (int i = 0; i < MCHUNK; ++i) {
        const int j = ch * MCHUNK + i;
        const int base = ch * 49 + i * 6;
        const float4 r0 = sT[base + 0];
        const float4 r1 = sT[base + 1];
        const float4 r2 = sT[base + 2];
        const float4 r3 = sT[base + 3];
        const float4 r4 = sT[base + 4];
        const float4 r5 = sT[base + 5];
        const float ax = r0.x, ay = r0.y, az = r0.z, nna = r0.w;
        const float abx = r1.x, aby = r1.y, abz = r1.z, rab2 = r1.w;
        const float acx = r2.x, acy = r2.y, acz = r2.z, rac2 = r2.w;
        const float cbx = r3.x, cby = r3.y, cbz = r3.z, rcb2 = r3.w;
        const float nx = r4.x, ny = r4.y, nz = r4.z, abac = r4.w;
        const float naba = r5.x, naca = r5.y, ab2 = r5.z, ac2 = r5.w;

#pragma unroll
        for (int np = 0; np < NPT; ++np) {
            const float d1 = fmaf(abz, pz[np], fmaf(aby, py[np], fmaf(abx, px[np], naba)));
            const float d2 = fmaf(acz, pz[np], fmaf(acy, py[np], fmaf(acx, px[np], naca)));
            const float h  = fmaf(nz,  pz[np], fmaf(ny,  py[np], fmaf(nx,  px[np], nna)));
            const float d3 = d1 - ab2;    // identity: d1-d3 == ab.ab
            const float d4 = d2 - abac;   // identity: ac.b - ac.a == ab.ac
            const float d5 = d1 - abac;   // identity: ab.c - ab.a == ab.ac
            const float d6 = d2 - ac2;    // identity: d2-d6 == ac.ac

            const float vc = fmaf(d1, d4, -(d3*d2));
            const float vb = fmaf(d5, d2, -(d1*d6));
            const float va = fmaf(d3, d6, -(d5*d4));
            const float t43 = d4 - d3;

            const float v_ab = clip01(d1 * rab2);
            const float v_ac = clip01(d2 * rac2);
            const float v_bc = clip01(t43 * rcb2);

            const float apx = px[np] - ax, apy = py[np] - ay, apz = pz[np] - az;
            const float bpx = apx - abx, bpy = apy - aby, bpz = apz - abz;

            float ex = fmaf(-v_ab, abx, apx), ey = fmaf(-v_ab, aby, apy), ez = fmaf(-v_ab, abz, apz);
            const float dAB = fmaf(ez, ez, fmaf(ey, ey, ex*ex));
            ex = fmaf(-v_ac, acx, apx); ey = fmaf(-v_ac, acy, apy); ez = fmaf(-v_ac, acz, apz);
            const float dAC = fmaf(ez, ez, fmaf(ey, ey, ex*ex));
            ex = fmaf(-v_bc, cbx, bpx); ey = fmaf(-v_bc, cby, bpy); ez = fmaf(-v_bc, cbz, bpz);
            const float dBC = fmaf(ez, ez, fmaf(ey, ey, ex*ex));
            const float dF = h * h;

            const float mv = fminf(fminf(va, vb), vc);         // v_min3
            const float dseg = fminf(fminf(dAB, dAC), dBC);
            const float dist2 = (mv >= 0.0f) ? dF : dseg;

            // strict < ascending j: first-occurrence tie-break like np.argmin
            if (dist2 < bestd[np]) { bestd[np] = dist2; bestj[np] = j; }
        }
    }

    // ---- in-wave butterfly over the 8 chunks this wave holds ----
#pragma unroll
    for (int np = 0; np < NPT; ++np) {
        for (int off = 8; off <= 32; off <<= 1) {
            const float od = __shfl_xor(bestd[np], off, 64);
            const int   oj = __shfl_xor(bestj[np], off, 64);
            if (od < bestd[np] || (od == bestd[np] && oj < bestj[np])) {
                bestd[np] = od; bestj[np] = oj;
            }
        }
    }
    const int lane = t & 63;
    const int w    = t >> 6;                 // wave [0,8)
    if (lane < PTS) {
#pragma unroll
        for (int np = 0; np < NPT; ++np) {
            sPd[np][w * PTS + lane] = bestd[np];
            sPj[np][w * PTS + lane] = bestj[np];
        }
    }
    __syncthreads();

    // ---- final reduce + phase 2: exact recompute for the winner ----
    if (t < 32) {
        const int np = t >> 3;
        const int p  = t & 7;
        float bd = INFINITY; int bj = 0;
        for (int k = 0; k < 8; ++k) {        // waves ascend -> chunks ascend -> j ascends
            const float dk = sPd[np][k * PTS + p];
            const int   jk = sPj[np][k * PTS + p];
            if (dk < bd || (dk == bd && jk < bj)) { bd = dk; bj = jk; }
        }
        // raw coords from global (L2-warm; 32 threads only)
        const float* g1 = tri1 + ((size_t)b * MM + bj) * 3;
        const float* g2 = tri2 + ((size_t)b * MM + bj) * 3;
        const float* g3 = tri3 + ((size_t)b * MM + bj) * 3;
        const int gidx = b * NN + pb * 32 + t;   // t == np*8 + p
        float dist2; int reg;
        exact_pair(xyz1[gidx*3+0], xyz1[gidx*3+1], xyz1[gidx*3+2],
                   g1[0], g1[1], g1[2],
                   g2[0], g2[1], g2[2],
                   g3[0], g3[1], g3[2],
                   &dist2, &reg);
        out[gidx]             = dist2;
        out[BB*NN + gidx]     = (float)reg;
        out[2*BB*NN + gidx]   = (float)bj;
    }
}

extern "C" void kernel_launch(void* const* d_in, const int* in_sizes, int n_in,
                              void* d_out, int out_size, void* d_ws, size_t ws_size,
                              hipStream_t stream) {
    const float* xyz1 = (const float*)d_in[0];
    const float* tri1 = (const float*)d_in[1];
    const float* tri2 = (const float*)d_in[2];
    const float* tri3 = (const float*)d_in[3];
    float* out = (float*)d_out;

    dim3 grid(BB * (NN / 32));    // 512 blocks -> 2 blocks/CU, 16 waves/CU
    dim3 block(TPB);              // 512 threads
    tridist_kernel<<<grid, block, 0, stream>>>(xyz1, tri1, tri2, tri3, out);
}

// Round 8
// 72.161 us; speedup vs baseline: 1.4685x; 1.0191x over previous
//
#include <hip/hip_runtime.h>
#include <math.h>

#define BB 4
#define NN 4096
#define MM 512
#define PTS 8                  // point-slots per block
#define NPT 4                  // points per thread = 2 packed float2 groups
#define CHUNKS 64              // m-chunks
#define MCHUNK (MM / CHUNKS)   // 8 triangles per chunk
#define TPB 512

typedef float v2 __attribute__((ext_vector_type(2)));

__device__ __forceinline__ v2 pfma(v2 a, v2 b, v2 c) {
    return __builtin_elementwise_fma(a, b, c);   // -> v_pk_fma_f32 on gfx950
}
__device__ __forceinline__ v2 pmin(v2 a, v2 b) { return __builtin_elementwise_min(a, b); }
__device__ __forceinline__ v2 pmax(v2 a, v2 b) { return __builtin_elementwise_max(a, b); }
__device__ __forceinline__ v2 pclip01(v2 x) { return pmin(pmax(x, (v2)0.0f), (v2)1.0f); }

// reference _safe_div guard + hw rcp (~1 ulp) -- relative-class error, argmin-safe (R4-R7 validated)
__device__ __forceinline__ float safercp(float y) {
    float yy = (fabsf(y) < 1e-12f) ? 1.0f : y;
    return __builtin_amdgcn_rcpf(yy);
}

// exact IEEE version for phase-2 (matches reference bit-order, validated R1/R3/R6/R7)
__device__ __forceinline__ float safediv(float x, float y) {
    float yy = (fabsf(y) < 1e-12f) ? 1.0f : y;
    return x / yy;
}

__device__ __forceinline__ float clip01s(float x) {
    return fminf(fmaxf(x, 0.0f), 1.0f);
}

// Phase 2: exact reference-ordered Ericson for ONE pair (R1-validated numerics).
__device__ void exact_pair(float px, float py, float pz,
                           float ax, float ay, float az,
                           float bx, float by, float bz,
                           float cx, float cy, float cz,
                           float* dist2_out, int* reg_out) {
#pragma clang fp contract(off)
    const float abx = bx-ax, aby = by-ay, abz = bz-az;
    const float acx = cx-ax, acy = cy-ay, acz = cz-az;
    const float cbx = cx-bx, cby = cy-by, cbz = cz-bz;
    const float apx = px-ax, apy = py-ay, apz = pz-az;
    const float bpx = px-bx, bpy = py-by, bpz = pz-bz;
    const float cpx = px-cx, cpy = py-cy, cpz = pz-cz;

    const float d1 = abx*apx + aby*apy + abz*apz;
    const float d2 = acx*apx + acy*apy + acz*apz;
    const float d3 = abx*bpx + aby*bpy + abz*bpz;
    const float d4 = acx*bpx + acy*bpy + acz*bpz;
    const float d5 = abx*cpx + aby*cpy + abz*cpz;
    const float d6 = acx*cpx + acy*cpy + acz*cpz;

    const float vc = d1*d4 - d3*d2;
    const float vb = d5*d2 - d1*d6;
    const float va = d3*d6 - d5*d4;

    const float v_ab = clip01s(safediv(d1, d1 - d3));
    const float v_ac = clip01s(safediv(d2, d2 - d6));
    const float t43 = d4 - d3;
    const float t56 = d5 - d6;
    const float v_bc = clip01s(safediv(t43, t43 + t56));
    const float denom = va + vb + vc;
    const float v_f = safediv(vb, denom);
    const float w_f = safediv(vc, denom);

    float qx = ax + v_f*abx + w_f*acx;
    float qy = ay + v_f*aby + w_f*acy;
    float qz = az + v_f*abz + w_f*acz;
    int reg = 6;
    const bool c_bc = (va <= 0.0f) && (t43 >= 0.0f) && (t56 >= 0.0f);
    if (c_bc) { qx = bx + v_bc*cbx; qy = by + v_bc*cby; qz = bz + v_bc*cbz; reg = 5; }
    const bool c_ac = (vb <= 0.0f) && (d2 >= 0.0f) && (d6 <= 0.0f);
    if (c_ac) { qx = ax + v_ac*acx; qy = ay + v_ac*acy; qz = az + v_ac*acz; reg = 4; }
    const bool c_c = (d6 >= 0.0f) && (d5 <= d6);
    if (c_c) { qx = cx; qy = cy; qz = cz; reg = 2; }
    const bool c_ab = (vc <= 0.0f) && (d1 >= 0.0f) && (d3 <= 0.0f);
    if (c_ab) { qx = ax + v_ab*abx; qy = ay + v_ab*aby; qz = az + v_ab*abz; reg = 3; }
    const bool c_b = (d3 >= 0.0f) && (d4 <= d3);
    if (c_b) { qx = bx; qy = by; qz = bz; reg = 1; }
    const bool c_a = (d1 <= 0.0f) && (d2 <= 0.0f);
    if (c_a) { qx = ax; qy = ay; qz = az; reg = 0; }

    const float dx = px - qx;
    const float dy = py - qy;
    const float dz = pz - qz;
    *dist2_out = dx*dx + dy*dy + dz*dz;
    *reg_out = reg;
}

__global__ __launch_bounds__(TPB) void tridist_kernel(
    const float* __restrict__ xyz1, const float* __restrict__ tri1,
    const float* __restrict__ tri2, const float* __restrict__ tri3,
    float* __restrict__ out)
{
    // 6 float4 per record:
    //  r0[a.xyz  nna(-n.a)] r1[ab.xyz rab2] r2[ac.xyz rac2] r3[cb.xyz rcb2]
    //  r4[n.xyz  abac]      r5[naba(-ab.a) naca(-ac.a) ab2 ac2]
    // +1 float4 pad per group of 8 records (49 float4/group): the 8 records a
    // wave touches start on banks {0,4,...,28} -> conflict-free (R7-validated).
    __shared__ float4 sT[(MM / 8) * 49];      // 50176 B
    __shared__ float  sPd[NPT][64];
    __shared__ int    sPj[NPT][64];           // total 52224 B -> 2 blocks/CU

    const int t  = threadIdx.x;
    const int b  = blockIdx.x >> 7;          // 128 blocks per batch
    const int pb = blockIdx.x & 127;
    const int pt = t & (PTS - 1);
    const int ch = t >> 3;                   // chunk [0,64)

    // ---- stage + per-triangle precompute (one thread per triangle, TPB==MM) ----
    {
        const int jj = t;
        const float* g1 = tri1 + ((size_t)b * MM + jj) * 3;
        const float* g2 = tri2 + ((size_t)b * MM + jj) * 3;
        const float* g3 = tri3 + ((size_t)b * MM + jj) * 3;
        const float ax = g1[0], ay = g1[1], az = g1[2];
        const float bx = g2[0], by = g2[1], bz = g2[2];
        const float cx = g3[0], cy = g3[1], cz = g3[2];
        const float abx = bx-ax, aby = by-ay, abz = bz-az;
        const float acx = cx-ax, acy = cy-ay, acz = cz-az;
        const float cbx = cx-bx, cby = cy-by, cbz = cz-bz;
        const float aba  = fmaf(abz, az, fmaf(aby, ay, abx*ax));
        const float aca  = fmaf(acz, az, fmaf(acy, ay, acx*ax));
        const float ab2  = fmaf(abz, abz, fmaf(aby, aby, abx*abx));   // == d1-d3
        const float ac2  = fmaf(acz, acz, fmaf(acy, acy, acx*acx));   // == d2-d6
        const float cb2  = fmaf(cbz, cbz, fmaf(cby, cby, cbx*cbx));
        const float abac = fmaf(abz, acz, fmaf(aby, acy, abx*acx));
        const float nrx = fmaf(aby, acz, -(abz*acy));
        const float nry = fmaf(abz, acx, -(abx*acz));
        const float nrz = fmaf(abx, acy, -(aby*acx));
        const float n2  = fmaf(nrz, nrz, fmaf(nry, nry, nrx*nrx));
        const float rn  = __builtin_amdgcn_rsqf(fmaxf(n2, 1e-30f));
        const float nx = nrx*rn, ny = nry*rn, nz = nrz*rn;
        const float nna = -fmaf(nz, az, fmaf(ny, ay, nx*ax));
        const int base = (jj >> 3) * 49 + (jj & 7) * 6;
        sT[base + 0] = make_float4(ax, ay, az, nna);
        sT[base + 1] = make_float4(abx, aby, abz, safercp(ab2));
        sT[base + 2] = make_float4(acx, acy, acz, safercp(ac2));
        sT[base + 3] = make_float4(cbx, cby, cbz, safercp(cb2));
        sT[base + 4] = make_float4(nx, ny, nz, abac);
        sT[base + 5] = make_float4(-aba, -aca, ab2, ac2);
    }
    __syncthreads();

    // ---- 4 points per thread, packed as 2 x float2 ----
    v2 Px[2], Py[2], Pz[2];
#pragma unroll
    for (int np = 0; np < NPT; ++np) {
        const int gi = b * NN + pb * 32 + np * PTS + pt;
        Px[np >> 1][np & 1] = xyz1[gi*3 + 0];
        Py[np >> 1][np & 1] = xyz1[gi*3 + 1];
        Pz[np >> 1][np & 1] = xyz1[gi*3 + 2];
    }

    float bestd[NPT] = {INFINITY, INFINITY, INFINITY, INFINITY};
    int   bestj[NPT] = {0, 0, 0, 0};

    // ---- phase 1: packed min-form distance ----
    for (int i = 0; i < MCHUNK; ++i) {
        const int j = ch * MCHUNK + i;
        const int base = ch * 49 + i * 6;
        const float4 r0 = sT[base + 0];
        const float4 r1 = sT[base + 1];
        const float4 r2 = sT[base + 2];
        const float4 r3 = sT[base + 3];
        const float4 r4 = sT[base + 4];
        const float4 r5 = sT[base + 5];
        const float ax = r0.x, ay = r0.y, az = r0.z, nna = r0.w;
        const float abx = r1.x, aby = r1.y, abz = r1.z, rab2 = r1.w;
        const float acx = r2.x, acy = r2.y, acz = r2.z, rac2 = r2.w;
        const float cbx = r3.x, cby = r3.y, cbz = r3.z, rcb2 = r3.w;
        const float nx = r4.x, ny = r4.y, nz = r4.z, abac = r4.w;
        const float naba = r5.x, naca = r5.y, ab2 = r5.z, ac2 = r5.w;

#pragma unroll
        for (int g = 0; g < 2; ++g) {
            const v2 X = Px[g], Y = Py[g], Z = Pz[g];

            const v2 d1 = pfma((v2)abz, Z, pfma((v2)aby, Y, pfma((v2)abx, X, (v2)naba)));
            const v2 d2 = pfma((v2)acz, Z, pfma((v2)acy, Y, pfma((v2)acx, X, (v2)naca)));
            const v2 h  = pfma((v2)nz,  Z, pfma((v2)ny,  Y, pfma((v2)nx,  X, (v2)nna)));
            const v2 d3 = d1 - (v2)ab2;     // identity: d1-d3 == ab.ab
            const v2 d4 = d2 - (v2)abac;    // identity: ac.b - ac.a == ab.ac
            const v2 d5 = d1 - (v2)abac;    // identity: ab.c - ab.a == ab.ac
            const v2 d6 = d2 - (v2)ac2;     // identity: d2-d6 == ac.ac

            const v2 vc = pfma(d1, d4, -(d3*d2));
            const v2 vb = pfma(d5, d2, -(d1*d6));
            const v2 va = pfma(d3, d6, -(d5*d4));
            const v2 t43 = d4 - d3;

            const v2 v_ab = pclip01(d1 * (v2)rab2);
            const v2 v_ac = pclip01(d2 * (v2)rac2);
            const v2 v_bc = pclip01(t43 * (v2)rcb2);

            const v2 apx = X - (v2)ax, apy = Y - (v2)ay, apz = Z - (v2)az;
            const v2 bpx = apx - (v2)abx, bpy = apy - (v2)aby, bpz = apz - (v2)abz;

            v2 ex = pfma(-v_ab, (v2)abx, apx);
            v2 ey = pfma(-v_ab, (v2)aby, apy);
            v2 ez = pfma(-v_ab, (v2)abz, apz);
            const v2 dAB = pfma(ez, ez, pfma(ey, ey, ex*ex));
            ex = pfma(-v_ac, (v2)acx, apx);
            ey = pfma(-v_ac, (v2)acy, apy);
            ez = pfma(-v_ac, (v2)acz, apz);
            const v2 dAC = pfma(ez, ez, pfma(ey, ey, ex*ex));
            ex = pfma(-v_bc, (v2)cbx, bpx);
            ey = pfma(-v_bc, (v2)cby, bpy);
            ez = pfma(-v_bc, (v2)cbz, bpz);
            const v2 dBC = pfma(ez, ez, pfma(ey, ey, ex*ex));
            const v2 dF = h * h;

            const v2 mv   = pmin(pmin(va, vb), vc);
            const v2 dseg = pmin(pmin(dAB, dAC), dBC);

#pragma unroll
            for (int c = 0; c < 2; ++c) {
                const float dist2 = (mv[c] >= 0.0f) ? dF[c] : dseg[c];
                const int np = g * 2 + c;
                // strict < ascending j: first-occurrence tie-break like np.argmin
                if (dist2 < bestd[np]) { bestd[np] = dist2; bestj[np] = j; }
            }
        }
    }

    // ---- in-wave butterfly over the 8 chunks this wave holds ----
#pragma unroll
    for (int np = 0; np < NPT; ++np) {
        for (int off = 8; off <= 32; off <<= 1) {
            const float od = __shfl_xor(bestd[np], off, 64);
            const int   oj = __shfl_xor(bestj[np], off, 64);
            if (od < bestd[np] || (od == bestd[np] && oj < bestj[np])) {
                bestd[np] = od; bestj[np] = oj;
            }
        }
    }
    const int lane = t & 63;
    const int w    = t >> 6;                 // wave [0,8)
    if (lane < PTS) {
#pragma unroll
        for (int np = 0; np < NPT; ++np) {
            sPd[np][w * PTS + lane] = bestd[np];
            sPj[np][w * PTS + lane] = bestj[np];
        }
    }
    __syncthreads();

    // ---- final reduce + phase 2: exact recompute for the winner ----
    if (t < 32) {
        const int np = t >> 3;
        const int p  = t & 7;
        float bd = INFINITY; int bj = 0;
        for (int k = 0; k < 8; ++k) {        // waves ascend -> chunks ascend -> j ascends
            const float dk = sPd[np][k * PTS + p];
            const int   jk = sPj[np][k * PTS + p];
            if (dk < bd || (dk == bd && jk < bj)) { bd = dk; bj = jk; }
        }
        const float* g1 = tri1 + ((size_t)b * MM + bj) * 3;
        const float* g2 = tri2 + ((size_t)b * MM + bj) * 3;
        const float* g3 = tri3 + ((size_t)b * MM + bj) * 3;
        const int gidx = b * NN + pb * 32 + t;   // t == np*8 + p
        float dist2; int reg;
        exact_pair(xyz1[gidx*3+0], xyz1[gidx*3+1], xyz1[gidx*3+2],
                   g1[0], g1[1], g1[2],
                   g2[0], g2[1], g2[2],
                   g3[0], g3[1], g3[2],
                   &dist2, &reg);
        out[gidx]             = dist2;
        out[BB*NN + gidx]     = (float)reg;
        out[2*BB*NN + gidx]   = (float)bj;
    }
}

extern "C" void kernel_launch(void* const* d_in, const int* in_sizes, int n_in,
                              void* d_out, int out_size, void* d_ws, size_t ws_size,
                              hipStream_t stream) {
    const float* xyz1 = (const float*)d_in[0];
    const float* tri1 = (const float*)d_in[1];
    const float* tri2 = (const float*)d_in[2];
    const float* tri3 = (const float*)d_in[3];
    float* out = (float*)d_out;

    dim3 grid(BB * (NN / 32));    // 512 blocks -> 2 blocks/CU, 16 waves/CU
    dim3 block(TPB);              // 512 threads
    tridist_kernel<<<grid, block, 0, stream>>>(xyz1, tri1, tri2, tri3, out);
}